// Round 2
// baseline (2693.655 us; speedup 1.0000x reference)
//
#include <hip/hip_runtime.h>
#include <hip/hip_bf16.h>
#include <math.h>

#define NN 100000
#define DD 128
#define OUT_DIM 256
#define HOPS 3
#define EDGES 640000
#define AGG_LD 384          // 3 hops * 128 contiguous per node

#define BM 64
#define BN 64
#define KC 32

__device__ __forceinline__ float silu(float v) {
    return v / (1.0f + expf(-v));
}

// ---------------------------------------------------------------------------
// Scatter-add: agg[t%N][ (t/N)*128 + d ] += x[s%N][d]
// 8 edges per 256-thread block, 32 lanes/edge, float4 per lane.
// ---------------------------------------------------------------------------
__global__ __launch_bounds__(256) void scatter_kernel(
    const float* __restrict__ x, const int* __restrict__ target,
    const int* __restrict__ src, float* __restrict__ agg) {
    int tid = threadIdx.x;
    int e = blockIdx.x * 8 + (tid >> 5);
    if (e >= EDGES) return;
    int lane = tid & 31;
    int t = target[e];
    int s = src[e];
    int sn = s % NN;
    int hop = t / NN;
    int tn = t - hop * NN;
    float4 v = *(const float4*)(x + (size_t)sn * DD + lane * 4);
    float* dst = agg + (size_t)tn * AGG_LD + hop * DD + lane * 4;
    atomicAdd(dst + 0, v.x);
    atomicAdd(dst + 1, v.y);
    atomicAdd(dst + 2, v.z);
    atomicAdd(dst + 3, v.w);
}

// ---------------------------------------------------------------------------
// GEMM 1: feats[N,512] (virtual concat of x[N,128] and agg[N,384]) times
// Wcat[512, 512] where cols 0-255 = W_in (silu -> h0), cols 256-511 = W_skip
// (plain -> gskip, stored in d_out).
// 64x64 tile, 16x16 threads, 4x4 micro-tile.
// ---------------------------------------------------------------------------
__global__ __launch_bounds__(256) void gemm_in_skip(
    const float* __restrict__ x, const float* __restrict__ agg,
    const float* __restrict__ Win, const float* __restrict__ bin,
    const float* __restrict__ Wskip, const float* __restrict__ bskip,
    float* __restrict__ h0, float* __restrict__ gskip) {
    __shared__ float As[KC][BM + 4];
    __shared__ float Bs[KC][BN];

    int row0 = blockIdx.x * BM;
    int colBase = blockIdx.y * BN;               // 0..511
    bool isSkip = colBase >= OUT_DIM;
    const float* W = isSkip ? Wskip : Win;
    const float* bias = isSkip ? bskip : bin;
    int wcol0 = isSkip ? colBase - OUT_DIM : colBase;

    int tid = threadIdx.x;
    int tr = tid >> 4, tc = tid & 15;
    float acc[4][4] = {};

    for (int k0 = 0; k0 < 512; k0 += KC) {
        const float* Abase;
        int ldA, koff;
        if (k0 < DD) { Abase = x;   ldA = DD;     koff = k0; }
        else         { Abase = agg; ldA = AGG_LD; koff = k0 - DD; }

        #pragma unroll
        for (int l = 0; l < 2; ++l) {
            int f = tid + l * 256;                // 0..511 float4 slots
            int r  = f >> 3;                      // 0..63 row in tile
            int kq = (f & 7) << 2;                // 0..28 k in tile
            int grow = row0 + r;
            float4 v = make_float4(0.f, 0.f, 0.f, 0.f);
            if (grow < NN)
                v = *(const float4*)(Abase + (size_t)grow * ldA + koff + kq);
            As[kq + 0][r] = v.x;
            As[kq + 1][r] = v.y;
            As[kq + 2][r] = v.z;
            As[kq + 3][r] = v.w;
        }
        #pragma unroll
        for (int l = 0; l < 2; ++l) {
            int f = tid + l * 256;
            int kr = f >> 4;                      // 0..31
            int cq = (f & 15) << 2;               // 0..60
            *(float4*)&Bs[kr][cq] =
                *(const float4*)(W + (size_t)(k0 + kr) * OUT_DIM + wcol0 + cq);
        }
        __syncthreads();

        #pragma unroll
        for (int k = 0; k < KC; ++k) {
            float4 a = *(const float4*)&As[k][tr * 4];
            float4 b = *(const float4*)&Bs[k][tc * 4];
            float av[4] = {a.x, a.y, a.z, a.w};
            float bv[4] = {b.x, b.y, b.z, b.w};
            #pragma unroll
            for (int i = 0; i < 4; ++i)
                #pragma unroll
                for (int j = 0; j < 4; ++j)
                    acc[i][j] += av[i] * bv[j];
        }
        __syncthreads();
    }

    int wc = wcol0 + tc * 4;
    float bb[4];
    #pragma unroll
    for (int j = 0; j < 4; ++j) bb[j] = bias[wc + j];

    #pragma unroll
    for (int i = 0; i < 4; ++i) {
        int grow = row0 + tr * 4 + i;
        if (grow >= NN) continue;
        #pragma unroll
        for (int j = 0; j < 4; ++j) {
            float v = acc[i][j] + bb[j];
            if (!isSkip) {
                h0[(size_t)grow * OUT_DIM + wc + j] = silu(v);
            } else {
                gskip[(size_t)grow * OUT_DIM + wc + j] = v;
            }
        }
    }
}

// ---------------------------------------------------------------------------
// Generic K=256 GEMM: C = opt_silu(A @ W + b [+ res1 [+ res2]])
// ---------------------------------------------------------------------------
__global__ __launch_bounds__(256) void gemm256(
    const float* __restrict__ A, const float* __restrict__ W,
    const float* __restrict__ bias, const float* __restrict__ res1,
    const float* __restrict__ res2, float* __restrict__ C, int applySilu) {
    __shared__ float As[KC][BM + 4];
    __shared__ float Bs[KC][BN];

    int row0 = blockIdx.x * BM;
    int col0 = blockIdx.y * BN;

    int tid = threadIdx.x;
    int tr = tid >> 4, tc = tid & 15;
    float acc[4][4] = {};

    for (int k0 = 0; k0 < OUT_DIM; k0 += KC) {
        #pragma unroll
        for (int l = 0; l < 2; ++l) {
            int f = tid + l * 256;
            int r  = f >> 3;
            int kq = (f & 7) << 2;
            int grow = row0 + r;
            float4 v = make_float4(0.f, 0.f, 0.f, 0.f);
            if (grow < NN)
                v = *(const float4*)(A + (size_t)grow * OUT_DIM + k0 + kq);
            As[kq + 0][r] = v.x;
            As[kq + 1][r] = v.y;
            As[kq + 2][r] = v.z;
            As[kq + 3][r] = v.w;
        }
        #pragma unroll
        for (int l = 0; l < 2; ++l) {
            int f = tid + l * 256;
            int kr = f >> 4;
            int cq = (f & 15) << 2;
            *(float4*)&Bs[kr][cq] =
                *(const float4*)(W + (size_t)(k0 + kr) * OUT_DIM + col0 + cq);
        }
        __syncthreads();

        #pragma unroll
        for (int k = 0; k < KC; ++k) {
            float4 a = *(const float4*)&As[k][tr * 4];
            float4 b = *(const float4*)&Bs[k][tc * 4];
            float av[4] = {a.x, a.y, a.z, a.w};
            float bv[4] = {b.x, b.y, b.z, b.w};
            #pragma unroll
            for (int i = 0; i < 4; ++i)
                #pragma unroll
                for (int j = 0; j < 4; ++j)
                    acc[i][j] += av[i] * bv[j];
        }
        __syncthreads();
    }

    int col = col0 + tc * 4;
    float bb[4];
    #pragma unroll
    for (int j = 0; j < 4; ++j) bb[j] = bias[col + j];

    #pragma unroll
    for (int i = 0; i < 4; ++i) {
        int grow = row0 + tr * 4 + i;
        if (grow >= NN) continue;
        size_t base = (size_t)grow * OUT_DIM + col;
        #pragma unroll
        for (int j = 0; j < 4; ++j) {
            float v = acc[i][j] + bb[j];
            if (res1) v += res1[base + j];
            if (res2) v += res2[base + j];
            if (applySilu) v = silu(v);
            C[base + j] = v;
        }
    }
}

extern "C" void kernel_launch(void* const* d_in, const int* in_sizes, int n_in,
                              void* d_out, int out_size, void* d_ws, size_t ws_size,
                              hipStream_t stream) {
    const float* x      = (const float*)d_in[0];
    const int*   target = (const int*)d_in[1];
    const int*   src    = (const int*)d_in[2];
    const float* W_in   = (const float*)d_in[3];
    const float* b_in   = (const float*)d_in[4];
    const float* W1_0   = (const float*)d_in[5];
    const float* b1_0   = (const float*)d_in[6];
    const float* W2_0   = (const float*)d_in[7];
    const float* b2_0   = (const float*)d_in[8];
    const float* W1_1   = (const float*)d_in[9];
    const float* b1_1   = (const float*)d_in[10];
    const float* W2_1   = (const float*)d_in[11];
    const float* b2_1   = (const float*)d_in[12];
    const float* W_skip = (const float*)d_in[13];
    const float* b_skip = (const float*)d_in[14];

    float* out = (float*)d_out;

    // workspace layout (floats):
    //   agg : N*384   (zeroed; also reused later as t / t2 scratch)
    //   h0  : N*256
    //   h1  : N*256
    float* agg = (float*)d_ws;
    float* h0  = agg + (size_t)NN * AGG_LD;
    float* h1  = h0 + (size_t)NN * OUT_DIM;
    float* t   = agg;   // reuse agg space after gemm_in_skip consumed it

    // 1. zero aggregate buffer
    hipMemsetAsync(agg, 0, (size_t)NN * AGG_LD * sizeof(float), stream);

    // 2. scatter-add
    scatter_kernel<<<EDGES / 8, 256, 0, stream>>>(x, target, src, agg);

    const int GRID_M = (NN + BM - 1) / BM;   // 1563

    // 3. h0 = silu(feats@W_in + b_in); gskip = feats@W_skip + b_skip -> d_out
    gemm_in_skip<<<dim3(GRID_M, 8), 256, 0, stream>>>(
        x, agg, W_in, b_in, W_skip, b_skip, h0, out);

    // 4. residual block 0
    gemm256<<<dim3(GRID_M, 4), 256, 0, stream>>>(
        h0, W1_0, b1_0, nullptr, nullptr, t, 1);          // t = silu(h0@W1_0+b)
    gemm256<<<dim3(GRID_M, 4), 256, 0, stream>>>(
        t, W2_0, b2_0, h0, nullptr, h1, 0);               // h1 = t@W2_0+b + h0

    // 5. residual block 1 (t buffer reused), fuse final +gskip
    gemm256<<<dim3(GRID_M, 4), 256, 0, stream>>>(
        h1, W1_1, b1_1, nullptr, nullptr, t, 1);          // t = silu(h1@W1_1+b)
    gemm256<<<dim3(GRID_M, 4), 256, 0, stream>>>(
        t, W2_1, b2_1, h1, out, out, 0);                  // out = t@W2_1+b + h1 + gskip
}

// Round 3
// 1663.392 us; speedup vs baseline: 1.6194x; 1.6194x over previous
//
#include <hip/hip_runtime.h>
#include <math.h>

#define NN 100000
#define DD 128
#define OUT_DIM 256
#define HOPS 3
#define EDGES 640000
#define TGT (HOPS*NN)          // 300000

typedef short bf16x8 __attribute__((ext_vector_type(8)));
typedef float f32x4 __attribute__((ext_vector_type(4)));

__device__ __forceinline__ unsigned short f2bf(float f) {
    unsigned u = __float_as_uint(f);
    unsigned r = u + 0x7FFFu + ((u >> 16) & 1u);   // RNE
    return (unsigned short)(r >> 16);
}
__device__ __forceinline__ float bf2f(unsigned short s) {
    return __uint_as_float(((unsigned)s) << 16);
}
__device__ __forceinline__ float silu(float v) { return v / (1.0f + expf(-v)); }

// ---------------------------------------------------------------------------
// CSR build: histogram -> block scan -> partial scan -> add-back -> fill
// ---------------------------------------------------------------------------
__global__ __launch_bounds__(256) void k_hist(const int* __restrict__ tgt,
                                              int* __restrict__ cnt) {
    int e = blockIdx.x * 256 + threadIdx.x;          // grid covers EDGES exactly
    atomicAdd(&cnt[tgt[e]], 1);
}

__global__ __launch_bounds__(512) void k_scanb(const int* __restrict__ cnt,
                                               int* __restrict__ off,
                                               int* __restrict__ part, int n) {
    __shared__ int s[512];
    int tid = threadIdx.x;
    int g = blockIdx.x * 512 + tid;
    int v = (g < n) ? cnt[g] : 0;
    s[tid] = v;
    __syncthreads();
    for (int d = 1; d < 512; d <<= 1) {
        int a = (tid >= d) ? s[tid - d] : 0;
        __syncthreads();
        s[tid] += a;
        __syncthreads();
    }
    if (g < n) off[g] = s[tid] - v;                  // exclusive
    if (tid == 511) part[blockIdx.x] = s[511];
}

__global__ __launch_bounds__(1024) void k_scanp(int* __restrict__ part, int n) {
    __shared__ int s[1024];
    int t = threadIdx.x;
    s[t] = (t < n) ? part[t] : 0;
    __syncthreads();
    for (int d = 1; d < 1024; d <<= 1) {
        int a = (t >= d) ? s[t - d] : 0;
        __syncthreads();
        s[t] += a;
        __syncthreads();
    }
    if (t < n) part[t] = s[t];                       // inclusive
}

__global__ __launch_bounds__(512) void k_addoff(int* __restrict__ off,
                                                const int* __restrict__ part,
                                                int* __restrict__ cursor, int n) {
    int g = blockIdx.x * 512 + threadIdx.x;
    if (g >= n) return;
    int add = (blockIdx.x > 0) ? part[blockIdx.x - 1] : 0;
    int o = off[g] + add;
    off[g] = o;
    cursor[g] = o;
}

__global__ __launch_bounds__(256) void k_fill(const int* __restrict__ tgt,
                                              const int* __restrict__ src,
                                              int* __restrict__ cursor,
                                              int* __restrict__ esrc) {
    int e = blockIdx.x * 256 + threadIdx.x;
    int t = tgt[e];
    int p = atomicAdd(&cursor[t], 1);
    esrc[p] = src[e] % NN;                           // store source node id
}

// ---------------------------------------------------------------------------
// Gather-aggregate + feats build (bf16). Virtual rows r in [0, 4N):
//   r < N        : feats[r][0:128]   = bf16(x[r])
//   r = N + t    : feats[t%N][128+ (t/N)*128 : ...] = bf16( sum x[esrc] )
// One 64-lane wave per row, 2 floats per lane.
// ---------------------------------------------------------------------------
__global__ __launch_bounds__(256) void k_aggfeats(const float* __restrict__ x,
                                                  const int* __restrict__ off,
                                                  const int* __restrict__ cur,
                                                  const int* __restrict__ esrc,
                                                  unsigned* __restrict__ feats) {
    int lane = threadIdx.x & 63;
    int r = blockIdx.x * 4 + (threadIdx.x >> 6);     // grid covers 4N exactly
    const float2* x2 = (const float2*)x;
    if (r < NN) {
        float2 v = x2[(size_t)r * 64 + lane];
        feats[(size_t)r * 256 + lane] =
            (unsigned)f2bf(v.x) | ((unsigned)f2bf(v.y) << 16);
    } else {
        int t = r - NN;                              // [0, 3N)
        int hop = t / NN;
        int tn = t - hop * NN;
        int b = off[t], e = cur[t];                  // cur==off+cnt after fill
        float ax = 0.f, ay = 0.f;
        for (int i = b; i < e; ++i) {
            int sn = esrc[i];
            float2 v = x2[(size_t)sn * 64 + lane];
            ax += v.x; ay += v.y;
        }
        feats[(size_t)tn * 256 + 64 + hop * 64 + lane] =
            (unsigned)f2bf(ax) | ((unsigned)f2bf(ay) << 16);
    }
}

// ---------------------------------------------------------------------------
// Weight prep: bf16 + transpose. Wt[c][k] layout (LD=K) so B-fragments are
// 16B-contiguous loads.  Wt1: 512 cols x 512 k  (cols 0-255=W_in, 256-511=W_skip)
// Wt25: four 256x256 blocks (W1_0, W2_0, W1_1, W2_1)
// ---------------------------------------------------------------------------
__global__ __launch_bounds__(256) void k_wprep(
    const float* __restrict__ Win, const float* __restrict__ Wskip,
    const float* __restrict__ W10, const float* __restrict__ W20,
    const float* __restrict__ W11, const float* __restrict__ W21,
    unsigned short* __restrict__ Wt1, unsigned short* __restrict__ Wt25) {
    int idx = blockIdx.x * 256 + threadIdx.x;        // grid = 2048 blocks
    if (idx < 262144) {
        int c = idx >> 9, k = idx & 511;
        float v = (c < 256) ? Win[k * 256 + c] : Wskip[k * 256 + (c - 256)];
        Wt1[idx] = f2bf(v);
    } else {
        int j = idx - 262144;
        int m = j >> 16, rr = j & 65535;
        int c = rr >> 8, k = rr & 255;
        const float* Wm = (m == 0) ? W10 : (m == 1) ? W20 : (m == 2) ? W11 : W21;
        Wt25[(size_t)m * 65536 + c * 256 + k] = f2bf(Wm[k * 256 + c]);
    }
}

// ---------------------------------------------------------------------------
// GEMM1: feats[N,512]bf16 @ Wt1 -> cols 0-255: h0 = silu (bf16)
//                                  cols 256-511: gskip (fp32, into d_out)
// Block = 4 waves, BM=128 (32 rows/wave), BN=256 per blockIdx.y.
// MFMA 16x16x32 bf16, fragments direct from global (L1/L2-resident W).
// ---------------------------------------------------------------------------
__global__ __launch_bounds__(256) void k_gemm1(
    const unsigned short* __restrict__ A, const unsigned short* __restrict__ Wt,
    const float* __restrict__ bin, const float* __restrict__ bskip,
    unsigned short* __restrict__ h0, float* __restrict__ gout) {
    const int K = 512;
    int w = threadIdx.x >> 6, lane = threadIdx.x & 63;
    int lr = lane & 15, lk = (lane >> 4) * 8;
    int rb = blockIdx.x * 128 + w * 32;
    int colbase = blockIdx.y * 256;

    f32x4 acc[2][16];
    #pragma unroll
    for (int i = 0; i < 2; ++i)
        #pragma unroll
        for (int j = 0; j < 16; ++j) acc[i][j] = (f32x4){0.f, 0.f, 0.f, 0.f};

    int r0 = rb + lr, r1 = rb + 16 + lr;
    const bf16x8 zero = {0, 0, 0, 0, 0, 0, 0, 0};
    #pragma unroll 1
    for (int ks = 0; ks < K / 32; ++ks) {
        bf16x8 a0 = (r0 < NN) ? *(const bf16x8*)(A + (size_t)r0 * K + ks * 32 + lk) : zero;
        bf16x8 a1 = (r1 < NN) ? *(const bf16x8*)(A + (size_t)r1 * K + ks * 32 + lk) : zero;
        #pragma unroll
        for (int cf = 0; cf < 16; ++cf) {
            bf16x8 b = *(const bf16x8*)(Wt + (size_t)(colbase + cf * 16 + lr) * K + ks * 32 + lk);
            acc[0][cf] = __builtin_amdgcn_mfma_f32_16x16x32_bf16(a0, b, acc[0][cf], 0, 0, 0);
            acc[1][cf] = __builtin_amdgcn_mfma_f32_16x16x32_bf16(a1, b, acc[1][cf], 0, 0, 0);
        }
    }

    int rq = (lane >> 4) * 4;
    if (blockIdx.y == 0) {
        #pragma unroll
        for (int rf = 0; rf < 2; ++rf)
            #pragma unroll
            for (int cf = 0; cf < 16; ++cf) {
                int c = cf * 16 + lr;
                float bb = bin[c];
                #pragma unroll
                for (int j = 0; j < 4; ++j) {
                    int r = rb + rf * 16 + rq + j;
                    if (r < NN) h0[(size_t)r * 256 + c] = f2bf(silu(acc[rf][cf][j] + bb));
                }
            }
    } else {
        #pragma unroll
        for (int rf = 0; rf < 2; ++rf)
            #pragma unroll
            for (int cf = 0; cf < 16; ++cf) {
                int c = cf * 16 + lr;
                float bb = bskip[c];
                #pragma unroll
                for (int j = 0; j < 4; ++j) {
                    int r = rb + rf * 16 + rq + j;
                    if (r < NN) gout[(size_t)r * 256 + c] = acc[rf][cf][j] + bb;
                }
            }
    }
}

// ---------------------------------------------------------------------------
// K=256 GEMM, epilogue templated:
//   EPI 0: C = silu(A@W + b)            -> bf16 Cb
//   EPI 1: C = A@W + b + res1(bf16)     -> bf16 Cb
//   EPI 2: C = A@W + b + res1 + res2f32 -> fp32 Cf
// ---------------------------------------------------------------------------
template <int EPI>
__global__ __launch_bounds__(256) void k_gemm256(
    const unsigned short* __restrict__ A, const unsigned short* __restrict__ Wt,
    const float* __restrict__ bias, const unsigned short* __restrict__ res1,
    const float* __restrict__ res2, unsigned short* __restrict__ Cb,
    float* __restrict__ Cf) {
    const int K = 256;
    int w = threadIdx.x >> 6, lane = threadIdx.x & 63;
    int lr = lane & 15, lk = (lane >> 4) * 8;
    int rb = blockIdx.x * 128 + w * 32;

    f32x4 acc[2][16];
    #pragma unroll
    for (int i = 0; i < 2; ++i)
        #pragma unroll
        for (int j = 0; j < 16; ++j) acc[i][j] = (f32x4){0.f, 0.f, 0.f, 0.f};

    int r0 = rb + lr, r1 = rb + 16 + lr;
    const bf16x8 zero = {0, 0, 0, 0, 0, 0, 0, 0};
    #pragma unroll 1
    for (int ks = 0; ks < K / 32; ++ks) {
        bf16x8 a0 = (r0 < NN) ? *(const bf16x8*)(A + (size_t)r0 * K + ks * 32 + lk) : zero;
        bf16x8 a1 = (r1 < NN) ? *(const bf16x8*)(A + (size_t)r1 * K + ks * 32 + lk) : zero;
        #pragma unroll
        for (int cf = 0; cf < 16; ++cf) {
            bf16x8 b = *(const bf16x8*)(Wt + (size_t)(cf * 16 + lr) * K + ks * 32 + lk);
            acc[0][cf] = __builtin_amdgcn_mfma_f32_16x16x32_bf16(a0, b, acc[0][cf], 0, 0, 0);
            acc[1][cf] = __builtin_amdgcn_mfma_f32_16x16x32_bf16(a1, b, acc[1][cf], 0, 0, 0);
        }
    }

    int rq = (lane >> 4) * 4;
    #pragma unroll
    for (int rf = 0; rf < 2; ++rf)
        #pragma unroll
        for (int cf = 0; cf < 16; ++cf) {
            int c = cf * 16 + lr;
            float bb = bias[c];
            #pragma unroll
            for (int j = 0; j < 4; ++j) {
                int r = rb + rf * 16 + rq + j;
                if (r >= NN) continue;
                size_t o = (size_t)r * 256 + c;
                float v = acc[rf][cf][j] + bb;
                if (EPI == 0) {
                    Cb[o] = f2bf(silu(v));
                } else if (EPI == 1) {
                    v += bf2f(res1[o]);
                    Cb[o] = f2bf(v);
                } else {
                    v += bf2f(res1[o]) + res2[o];
                    Cf[o] = v;
                }
            }
        }
}

extern "C" void kernel_launch(void* const* d_in, const int* in_sizes, int n_in,
                              void* d_out, int out_size, void* d_ws, size_t ws_size,
                              hipStream_t stream) {
    const float* x      = (const float*)d_in[0];
    const int*   target = (const int*)d_in[1];
    const int*   src    = (const int*)d_in[2];
    const float* W_in   = (const float*)d_in[3];
    const float* b_in   = (const float*)d_in[4];
    const float* W1_0   = (const float*)d_in[5];
    const float* b1_0   = (const float*)d_in[6];
    const float* W2_0   = (const float*)d_in[7];
    const float* b2_0   = (const float*)d_in[8];
    const float* W1_1   = (const float*)d_in[9];
    const float* b1_1   = (const float*)d_in[10];
    const float* W2_1   = (const float*)d_in[11];
    const float* b2_1   = (const float*)d_in[12];
    const float* W_skip = (const float*)d_in[13];
    const float* b_skip = (const float*)d_in[14];
    float* out = (float*)d_out;

    // workspace layout
    char* p = (char*)d_ws;
    unsigned short* feats = (unsigned short*)p; p += (size_t)NN * 512 * 2;   // 102.4 MB
    unsigned short* h0    = (unsigned short*)p; p += (size_t)NN * 256 * 2;   // 51.2 MB
    unsigned short* h1    = (unsigned short*)p; p += (size_t)NN * 256 * 2;
    unsigned short* tb    = (unsigned short*)p; p += (size_t)NN * 256 * 2;
    unsigned short* Wt1   = (unsigned short*)p; p += 512 * 512 * 2;
    unsigned short* Wt25  = (unsigned short*)p; p += 4 * 256 * 256 * 2;
    int* cnt    = (int*)p; p += (size_t)TGT * 4;
    int* off    = (int*)p; p += (size_t)TGT * 4;
    int* cursor = (int*)p; p += (size_t)TGT * 4;
    int* esrc   = (int*)p; p += (size_t)EDGES * 4;
    int* part   = (int*)p; p += 4096;

    const int SCAN_BLOCKS = (TGT + 511) / 512;        // 586

    // CSR build
    hipMemsetAsync(cnt, 0, (size_t)TGT * 4, stream);
    k_hist<<<EDGES / 256, 256, 0, stream>>>(target, cnt);
    k_scanb<<<SCAN_BLOCKS, 512, 0, stream>>>(cnt, off, part, TGT);
    k_scanp<<<1, 1024, 0, stream>>>(part, SCAN_BLOCKS);
    k_addoff<<<SCAN_BLOCKS, 512, 0, stream>>>(off, part, cursor, TGT);
    k_fill<<<EDGES / 256, 256, 0, stream>>>(target, src, cursor, esrc);

    // gather-aggregate + bf16 feats build (4N virtual rows, 4 rows/block)
    k_aggfeats<<<(4 * NN) / 4, 256, 0, stream>>>(x, off, cursor, esrc,
                                                 (unsigned*)feats);

    // weight prep (independent of above)
    k_wprep<<<2048, 256, 0, stream>>>(W_in, W_skip, W1_0, W2_0, W1_1, W2_1,
                                      Wt1, Wt25);

    const int GM = (NN + 127) / 128;                  // 782

    // GEMM1: h0 = silu(feats@W_in+b), gskip -> d_out
    k_gemm1<<<dim3(GM, 2), 256, 0, stream>>>(feats, Wt1, b_in, b_skip, h0, out);

    // residual block 0
    k_gemm256<0><<<dim3(GM, 1), 256, 0, stream>>>(h0, Wt25 + 0 * 65536, b1_0,
                                                  nullptr, nullptr, tb, nullptr);
    k_gemm256<1><<<dim3(GM, 1), 256, 0, stream>>>(tb, Wt25 + 1 * 65536, b2_0,
                                                  h0, nullptr, h1, nullptr);
    // residual block 1, final fuse (+h1 residual + gskip)
    k_gemm256<0><<<dim3(GM, 1), 256, 0, stream>>>(h1, Wt25 + 2 * 65536, b1_1,
                                                  nullptr, nullptr, tb, nullptr);
    k_gemm256<2><<<dim3(GM, 1), 256, 0, stream>>>(tb, Wt25 + 3 * 65536, b2_1,
                                                  h1, out, nullptr, out);
}

// Round 4
// 787.942 us; speedup vs baseline: 3.4186x; 2.1111x over previous
//
#include <hip/hip_runtime.h>
#include <math.h>

#define NN 100000
#define DD 128
#define OUT_DIM 256
#define HOPS 3
#define EDGES 640000
#define TGT (HOPS*NN)          // 300000

typedef short bf16x8 __attribute__((ext_vector_type(8)));
typedef float f32x4 __attribute__((ext_vector_type(4)));

__device__ __forceinline__ unsigned short f2bf(float f) {
    unsigned u = __float_as_uint(f);
    unsigned r = u + 0x7FFFu + ((u >> 16) & 1u);   // RNE
    return (unsigned short)(r >> 16);
}
__device__ __forceinline__ float bf2f(unsigned short s) {
    return __uint_as_float(((unsigned)s) << 16);
}
__device__ __forceinline__ float silu(float v) { return v / (1.0f + expf(-v)); }

__device__ __forceinline__ void gload16(const unsigned short* g, unsigned short* l) {
    __builtin_amdgcn_global_load_lds(
        (const __attribute__((address_space(1))) void*)g,
        (__attribute__((address_space(3))) void*)l, 16, 0, 0);
}

// ---------------------------------------------------------------------------
// CSR build: histogram -> block scan -> partial scan -> add-back -> fill
// ---------------------------------------------------------------------------
__global__ __launch_bounds__(256) void k_hist(const int* __restrict__ tgt,
                                              int* __restrict__ cnt) {
    int e = blockIdx.x * 256 + threadIdx.x;
    atomicAdd(&cnt[tgt[e]], 1);
}

__global__ __launch_bounds__(512) void k_scanb(const int* __restrict__ cnt,
                                               int* __restrict__ off,
                                               int* __restrict__ part, int n) {
    __shared__ int s[512];
    int tid = threadIdx.x;
    int g = blockIdx.x * 512 + tid;
    int v = (g < n) ? cnt[g] : 0;
    s[tid] = v;
    __syncthreads();
    for (int d = 1; d < 512; d <<= 1) {
        int a = (tid >= d) ? s[tid - d] : 0;
        __syncthreads();
        s[tid] += a;
        __syncthreads();
    }
    if (g < n) off[g] = s[tid] - v;                  // exclusive
    if (tid == 511) part[blockIdx.x] = s[511];
}

__global__ __launch_bounds__(1024) void k_scanp(int* __restrict__ part, int n) {
    __shared__ int s[1024];
    int t = threadIdx.x;
    s[t] = (t < n) ? part[t] : 0;
    __syncthreads();
    for (int d = 1; d < 1024; d <<= 1) {
        int a = (t >= d) ? s[t - d] : 0;
        __syncthreads();
        s[t] += a;
        __syncthreads();
    }
    if (t < n) part[t] = s[t];                       // inclusive
}

__global__ __launch_bounds__(512) void k_addoff(int* __restrict__ off,
                                                const int* __restrict__ part,
                                                int* __restrict__ cursor, int n) {
    int g = blockIdx.x * 512 + threadIdx.x;
    if (g >= n) return;
    int add = (blockIdx.x > 0) ? part[blockIdx.x - 1] : 0;
    int o = off[g] + add;
    off[g] = o;
    cursor[g] = o;
}

__global__ __launch_bounds__(256) void k_fill(const int* __restrict__ tgt,
                                              const int* __restrict__ src,
                                              int* __restrict__ cursor,
                                              int* __restrict__ esrc) {
    int e = blockIdx.x * 256 + threadIdx.x;
    int t = tgt[e];
    int p = atomicAdd(&cursor[t], 1);
    esrc[p] = src[e] % NN;
}

// ---------------------------------------------------------------------------
// Gather-aggregate + feats build (bf16). One 64-lane wave per virtual row.
// ---------------------------------------------------------------------------
__global__ __launch_bounds__(256) void k_aggfeats(const float* __restrict__ x,
                                                  const int* __restrict__ off,
                                                  const int* __restrict__ cur,
                                                  const int* __restrict__ esrc,
                                                  unsigned* __restrict__ feats) {
    int lane = threadIdx.x & 63;
    int r = blockIdx.x * 4 + (threadIdx.x >> 6);
    const float2* x2 = (const float2*)x;
    if (r < NN) {
        float2 v = x2[(size_t)r * 64 + lane];
        feats[(size_t)r * 256 + lane] =
            (unsigned)f2bf(v.x) | ((unsigned)f2bf(v.y) << 16);
    } else {
        int t = r - NN;
        int hop = t / NN;
        int tn = t - hop * NN;
        int b = off[t], e = cur[t];
        float ax = 0.f, ay = 0.f;
        for (int i = b; i < e; ++i) {
            int sn = esrc[i];
            float2 v = x2[(size_t)sn * 64 + lane];
            ax += v.x; ay += v.y;
        }
        feats[(size_t)tn * 256 + 64 + hop * 64 + lane] =
            (unsigned)f2bf(ax) | ((unsigned)f2bf(ay) << 16);
    }
}

// ---------------------------------------------------------------------------
// Weight prep: bf16 + transpose to Wt[c][k] (LD=K).
// ---------------------------------------------------------------------------
__global__ __launch_bounds__(256) void k_wprep(
    const float* __restrict__ Win, const float* __restrict__ Wskip,
    const float* __restrict__ W10, const float* __restrict__ W20,
    const float* __restrict__ W11, const float* __restrict__ W21,
    unsigned short* __restrict__ Wt1, unsigned short* __restrict__ Wt25) {
    int idx = blockIdx.x * 256 + threadIdx.x;        // grid = 2048 blocks
    if (idx < 262144) {
        int c = idx >> 9, k = idx & 511;
        float v = (c < 256) ? Win[k * 256 + c] : Wskip[k * 256 + (c - 256)];
        Wt1[idx] = f2bf(v);
    } else {
        int j = idx - 262144;
        int m = j >> 16, rr = j & 65535;
        int c = rr >> 8, k = rr & 255;
        const float* Wm = (m == 0) ? W10 : (m == 1) ? W20 : (m == 2) ? W11 : W21;
        Wt25[(size_t)m * 65536 + c * 256 + k] = f2bf(Wm[k * 256 + c]);
    }
}

// ---------------------------------------------------------------------------
// Tiled MFMA GEMM (m97 structure): BM=128, BN=128, BK=64, 4 waves, each wave
// computes a 64x64 sub-tile (4x4 fragments of 16x16x32 bf16 MFMA).
// A[M,K] bf16 row-major; Wt[N,K] bf16 (i.e. B already transposed).
// EPI: 0: Cb = bf16(silu(v+b0))
//      1: Cb = bf16(v + b0 + res1)
//      2: Cf = v + b0 + res1 + res2
//      3: gemm1 dual: col<256 -> Cb = bf16(silu(v+b0)); col>=256 -> Cf = v+b1
// ---------------------------------------------------------------------------
template <int K, int EPI>
__global__ __launch_bounds__(256) void k_gemm_t(
    const unsigned short* __restrict__ A, const unsigned short* __restrict__ Wt,
    const float* __restrict__ bias0, const float* __restrict__ bias1,
    const unsigned short* __restrict__ res1, const float* __restrict__ res2,
    unsigned short* __restrict__ Cb, float* __restrict__ Cf) {
    __shared__ unsigned short As[128 * 64];
    __shared__ unsigned short Bs[128 * 64];

    const int tid = threadIdx.x;
    const int lane = tid & 63;
    const int w = tid >> 6;
    const int row0 = blockIdx.x * 128;
    const int col0 = blockIdx.y * 128;

    const int wr = (w >> 1) * 64;
    const int wc = (w & 1) * 64;
    const int lr = lane & 15;
    const int lk8 = (lane >> 4) * 8;

    f32x4 acc[4][4];
    #pragma unroll
    for (int m = 0; m < 4; ++m)
        #pragma unroll
        for (int n = 0; n < 4; ++n) acc[m][n] = (f32x4){0.f, 0.f, 0.f, 0.f};

    for (int k0 = 0; k0 < K; k0 += 64) {
        // stage A-tile [128 rows][64 k] and B-tile [128 cols][64 k] into LDS.
        // chunk = wave-uniform 1KB segment; HW writes lane's 16B at base+lane*16.
        #pragma unroll
        for (int i = 0; i < 4; ++i) {
            int chunk = i * 4 + w;
            int slot = chunk * 64 + lane;
            int r = slot >> 3;                       // 0..127
            int kq = (slot & 7) * 8;                 // 0..56
            gload16(A + (size_t)(row0 + r) * K + k0 + kq, As + chunk * 512);
            gload16(Wt + (size_t)(col0 + r) * K + k0 + kq, Bs + chunk * 512);
        }
        asm volatile("s_waitcnt vmcnt(0)" ::: "memory");
        __syncthreads();

        #pragma unroll
        for (int ks2 = 0; ks2 < 2; ++ks2) {
            bf16x8 af[4], bfr[4];
            #pragma unroll
            for (int m = 0; m < 4; ++m)
                af[m] = *(const bf16x8*)&As[(wr + m * 16 + lr) * 64 + ks2 * 32 + lk8];
            #pragma unroll
            for (int n = 0; n < 4; ++n)
                bfr[n] = *(const bf16x8*)&Bs[(wc + n * 16 + lr) * 64 + ks2 * 32 + lk8];
            #pragma unroll
            for (int m = 0; m < 4; ++m)
                #pragma unroll
                for (int n = 0; n < 4; ++n)
                    acc[m][n] = __builtin_amdgcn_mfma_f32_16x16x32_bf16(
                        af[m], bfr[n], acc[m][n], 0, 0, 0);
        }
        __syncthreads();
    }

    const int rq = (lane >> 4) * 4;
    #pragma unroll
    for (int m = 0; m < 4; ++m) {
        #pragma unroll
        for (int n = 0; n < 4; ++n) {
            int cg = col0 + wc + n * 16 + lr;        // global col in [0, N)
            float bb = (EPI == 3 && cg >= OUT_DIM) ? bias1[cg - OUT_DIM] : bias0[cg < OUT_DIM ? cg : 0];
            #pragma unroll
            for (int j = 0; j < 4; ++j) {
                int r = row0 + wr + m * 16 + rq + j;
                if (r >= NN) continue;
                float v = acc[m][n][j] + bb;
                if (EPI == 3) {
                    if (cg < OUT_DIM)
                        Cb[(size_t)r * OUT_DIM + cg] = f2bf(silu(v));
                    else
                        Cf[(size_t)r * OUT_DIM + (cg - OUT_DIM)] = v;
                } else if (EPI == 0) {
                    Cb[(size_t)r * OUT_DIM + cg] = f2bf(silu(v));
                } else if (EPI == 1) {
                    size_t o = (size_t)r * OUT_DIM + cg;
                    Cb[o] = f2bf(v + bf2f(res1[o]));
                } else {
                    size_t o = (size_t)r * OUT_DIM + cg;
                    Cf[o] = v + bf2f(res1[o]) + res2[o];
                }
            }
        }
    }
}

extern "C" void kernel_launch(void* const* d_in, const int* in_sizes, int n_in,
                              void* d_out, int out_size, void* d_ws, size_t ws_size,
                              hipStream_t stream) {
    const float* x      = (const float*)d_in[0];
    const int*   target = (const int*)d_in[1];
    const int*   src    = (const int*)d_in[2];
    const float* W_in   = (const float*)d_in[3];
    const float* b_in   = (const float*)d_in[4];
    const float* W1_0   = (const float*)d_in[5];
    const float* b1_0   = (const float*)d_in[6];
    const float* W2_0   = (const float*)d_in[7];
    const float* b2_0   = (const float*)d_in[8];
    const float* W1_1   = (const float*)d_in[9];
    const float* b1_1   = (const float*)d_in[10];
    const float* W2_1   = (const float*)d_in[11];
    const float* b2_1   = (const float*)d_in[12];
    const float* W_skip = (const float*)d_in[13];
    const float* b_skip = (const float*)d_in[14];
    float* out = (float*)d_out;

    // workspace layout
    char* p = (char*)d_ws;
    unsigned short* feats = (unsigned short*)p; p += (size_t)NN * 512 * 2;   // 102.4 MB
    unsigned short* h0    = (unsigned short*)p; p += (size_t)NN * 256 * 2;   // 51.2 MB
    unsigned short* h1    = (unsigned short*)p; p += (size_t)NN * 256 * 2;
    unsigned short* tb    = (unsigned short*)p; p += (size_t)NN * 256 * 2;
    unsigned short* Wt1   = (unsigned short*)p; p += 512 * 512 * 2;
    unsigned short* Wt25  = (unsigned short*)p; p += 4 * 256 * 256 * 2;
    int* cnt    = (int*)p; p += (size_t)TGT * 4;
    int* off    = (int*)p; p += (size_t)TGT * 4;
    int* cursor = (int*)p; p += (size_t)TGT * 4;
    int* esrc   = (int*)p; p += (size_t)EDGES * 4;
    int* part   = (int*)p; p += 4096;

    const int SCAN_BLOCKS = (TGT + 511) / 512;        // 586

    // CSR build
    hipMemsetAsync(cnt, 0, (size_t)TGT * 4, stream);
    k_hist<<<EDGES / 256, 256, 0, stream>>>(target, cnt);
    k_scanb<<<SCAN_BLOCKS, 512, 0, stream>>>(cnt, off, part, TGT);
    k_scanp<<<1, 1024, 0, stream>>>(part, SCAN_BLOCKS);
    k_addoff<<<SCAN_BLOCKS, 512, 0, stream>>>(off, part, cursor, TGT);
    k_fill<<<EDGES / 256, 256, 0, stream>>>(target, src, cursor, esrc);

    // gather-aggregate + bf16 feats build
    k_aggfeats<<<NN, 256, 0, stream>>>(x, off, cursor, esrc, (unsigned*)feats);

    // weight prep
    k_wprep<<<2048, 256, 0, stream>>>(W_in, W_skip, W1_0, W2_0, W1_1, W2_1,
                                      Wt1, Wt25);

    const int GM = (NN + 127) / 128;                  // 782

    // GEMM1: cols 0-255 -> h0 = silu(feats@W_in+b) bf16; cols 256-511 -> gskip f32 in d_out
    k_gemm_t<512, 3><<<dim3(GM, 4), 256, 0, stream>>>(
        feats, Wt1, b_in, b_skip, nullptr, nullptr, h0, out);

    // residual block 0
    k_gemm_t<256, 0><<<dim3(GM, 2), 256, 0, stream>>>(
        h0, Wt25 + 0 * 65536, b1_0, nullptr, nullptr, nullptr, tb, nullptr);
    k_gemm_t<256, 1><<<dim3(GM, 2), 256, 0, stream>>>(
        tb, Wt25 + 1 * 65536, b2_0, nullptr, h0, nullptr, h1, nullptr);

    // residual block 1, final fuse (+h1 residual + gskip already in d_out)
    k_gemm_t<256, 0><<<dim3(GM, 2), 256, 0, stream>>>(
        h1, Wt25 + 2 * 65536, b1_1, nullptr, nullptr, nullptr, tb, nullptr);
    k_gemm_t<256, 2><<<dim3(GM, 2), 256, 0, stream>>>(
        tb, Wt25 + 3 * 65536, b2_1, nullptr, h1, out, nullptr, out);
}